// Round 13
// baseline (65.813 us; speedup 1.0000x reference)
//
#include <hip/hip_runtime.h>
#include <hip/hip_bf16.h>
#include <stdint.h>

// KAN layer: out[n,o] = sum_j w[o,j] * spline(x[n,j]; coeffs[o,j,:]) + bias[o]
// N=1024, D_IN=128, D_OUT=128, K=8, Catmull-Rom, uniform grid [-1,1].
// fp32 in/out (proven R1/R2/R4).
//
// R12 post-mortem: staging/TLP lever exhausted (62.2; deltas -1.8/-0.95/-0.16).
// Residual ~9.8us kernel vs ~2us model: monolithic 16-wave blocks serialize
// 4 cold-HBM staging rounds behind one barrier. R13 = block-level K-split:
//  - memset(out) async, then grid 64m x 8o x 8k of 256-thr blocks
//  - each block: stage 4KB basis slice (16n x 16j) + 4KB W' slice (16o x 16j)
//    in ONE load round; 1 MFMA step/wave (4-way K-split of 128k);
//    4-way LDS reduce; fp32 atomicAdd into out (k-slice 0 adds bias)
//  - 12KB LDS, 8 blocks/CU -> latency hidden across blocks, 2 generations
//  - XOR swizzle on 16B units (^ row&7) -> phase-2 reads at structural
//    minimum aliasing (2-way = free, m136)
//
// MFMA 16x16x32 bf16 (R5..R12-verified): A/B-frag lane (mo=lane&15,
// q=lane>>4) holds [mo][k=32S+8q+kk]; C/D: col=lane&15, row=(lane>>4)*4+reg.

#define DIN 128
#define DOUT 128
#define KTOT 1024

typedef unsigned int u32;
typedef unsigned short u16;
typedef __attribute__((ext_vector_type(8))) short bf16x8;
typedef __attribute__((ext_vector_type(4))) float f32x4;

union H8 { u16 s[8]; uint4 v; };

__device__ __forceinline__ u16 f2b(float f) {
    union { __hip_bfloat16 h; u16 u; } c;
    c.h = __float2bfloat16(f);   // RNE
    return c.u;
}

__global__ __launch_bounds__(256, 8) void kan_slice(
    const float* __restrict__ x, const float* __restrict__ coeffs,
    const float* __restrict__ weights, const float* __restrict__ bias,
    float* __restrict__ out)
{
    __shared__ __align__(16) u16 sBas[16 * 128];    // 4 KB: 16 rows x 16 units
    __shared__ __align__(16) u16 sWp [16 * 128];    // 4 KB
    __shared__ float sC[4 * 256];                   // 4 KB partials

    const int tid  = threadIdx.x;
    const int wave = tid >> 6;                      // 0..3
    const int lane = tid & 63;
    const int n0 = blockIdx.x * 16;                 // 64 m-tiles
    const int o0 = blockIdx.y * 16;                 // 8 o-tiles
    const int js = blockIdx.z * 16;                 // j-slice start (16 j)

    // ---- Phase 1a: basis slice. 256 tasks (row, jl) ----
    {
        const int row = tid >> 4;
        const int jl = tid & 15;
        float xv = x[(n0 + row) * DIN + js + jl];
        xv = fminf(fmaxf(xv, -1.0f), 1.0f);
        const float t = (xv + 1.0f) * 3.5f;         // h = 2/7
        int idx = (int)t; idx = idx > 6 ? 6 : idx;  // t>=0: trunc==floor
        const float u = t - (float)idx;
        const float u2 = u * u, u3 = u2 * u;
        const float b0 = 0.5f * (-u3 + 2.0f * u2 - u);
        const float b1 = 0.5f * (3.0f * u3 - 5.0f * u2 + 2.0f);
        const float b2 = 0.5f * (-3.0f * u3 + 4.0f * u2 + u);
        const float b3 = 0.5f * (u3 - u2);
        float r[8];
        #pragma unroll
        for (int k = 0; k < 8; ++k) r[k] = 0.0f;
        const int i0 = idx > 0 ? idx - 1 : 0;       // accumulate = clip fix
        const int i3 = idx < 6 ? idx + 2 : 7;
        r[i0] += b0; r[idx] += b1; r[idx + 1] += b2; r[i3] += b3;
        H8 h;
        #pragma unroll
        for (int k = 0; k < 8; ++k) h.s[k] = f2b(r[k]);
        const int uu = jl ^ (row & 7);              // swizzled 16B unit
        *(uint4*)(sBas + row * 128 + uu * 8) = h.v;
    }

    // ---- Phase 1b: W' slice. 256 tasks (o, jl), 32B/lane coalesced ----
    {
        const int o = tid >> 4;
        const int jl = tid & 15;
        const float wv = weights[(o0 + o) * DIN + js + jl];
        const float* cp = coeffs + (o0 + o) * KTOT + (js + jl) * 8;
        const float4 c0 = *(const float4*)(cp);
        const float4 c1 = *(const float4*)(cp + 4);
        H8 h;
        h.s[0] = f2b(c0.x * wv); h.s[1] = f2b(c0.y * wv);
        h.s[2] = f2b(c0.z * wv); h.s[3] = f2b(c0.w * wv);
        h.s[4] = f2b(c1.x * wv); h.s[5] = f2b(c1.y * wv);
        h.s[6] = f2b(c1.z * wv); h.s[7] = f2b(c1.w * wv);
        const int uu = jl ^ (o & 7);
        *(uint4*)(sWp + o * 128 + uu * 8) = h.v;
    }
    __syncthreads();

    // ---- Phase 2: one MFMA step per wave (K=32 each, 128 total) ----
    const int mo = lane & 15;
    const int q  = lane >> 4;
    const int uu = (wave * 4 + q) ^ (mo & 7);       // 16B unit
    bf16x8 af = *(const bf16x8*)(sBas + mo * 128 + uu * 8);
    bf16x8 bf = *(const bf16x8*)(sWp  + mo * 128 + uu * 8);
    f32x4 acc = {0.0f, 0.0f, 0.0f, 0.0f};
    acc = __builtin_amdgcn_mfma_f32_16x16x32_bf16(af, bf, acc, 0, 0, 0);

    // ---- Phase 3: 4-way reduce + atomic accumulate ----
    #pragma unroll
    for (int r = 0; r < 4; ++r)
        sC[wave * 256 + (q * 4 + r) * 16 + mo] = acc[r];
    __syncthreads();

    {
        const int row = tid >> 4, col = tid & 15;
        float v = sC[tid] + sC[256 + tid] + sC[512 + tid] + sC[768 + tid];
        if (blockIdx.z == 0) v += bias[o0 + col];   // bias added exactly once
        atomicAdd(out + (n0 + row) * DOUT + o0 + col, v);
    }
}

extern "C" void kernel_launch(void* const* d_in, const int* in_sizes, int n_in,
                              void* d_out, int out_size, void* d_ws, size_t ws_size,
                              hipStream_t stream) {
    const float* x       = (const float*)d_in[0];
    const float* coeffs  = (const float*)d_in[1];
    const float* weights = (const float*)d_in[2];
    const float* bias    = (const float*)d_in[3];
    float* out = (float*)d_out;
    hipMemsetAsync(out, 0, (size_t)out_size * sizeof(float), stream);
    dim3 grid(1024 / 16, DOUT / 16, DIN / 16);      // 64 x 8 x 8 = 4096
    kan_slice<<<grid, 256, 0, stream>>>(x, coeffs, weights, bias, out);
}

// Round 14
// 63.984 us; speedup vs baseline: 1.0286x; 1.0286x over previous
//
#include <hip/hip_runtime.h>
#include <hip/hip_bf16.h>
#include <stdint.h>

// KAN layer: out[n,o] = sum_j w[o,j] * spline(x[n,j]; coeffs[o,j,:]) + bias[o]
// N=1024, D_IN=128, D_OUT=128, K=8, Catmull-Rom, uniform grid [-1,1].
// fp32 in/out (proven R1/R2/R4).
//
// R13 regressed (+3.6us: 4096-block atomics). Best = R12 (62.22): 1024-thr
// blocks, 64KB LDS, pure-LDS MFMA, 16-way K-split. Serial-graph model:
// 12.4us restores + 40us ws-poison fill + kernel ~9.8us.
//
// R14 = R12 + three micro-cuts:
//  K1: W' = w*c -> bf16 precomputed to ws ONCE (was converted 64x, once per
//      m-block). K2 phase-1b becomes a pure uint4 copy: zero VALU, half the
//      staged bytes (256KB bf16 vs 512KB fp32 + weights).
//  K2 grid: 1D 512 with XCD-patch swizzle (id&7 -> 16m x 4o patch per XCD)
//      to shrink per-XCD cold-L2 footprint after the 268MB fill flush.
//  Rest identical to R12 (XOR-swizzled LDS, 16-way K-split + reduce).
//
// MFMA 16x16x32 bf16 (R5..R13-verified): A/B-frag lane (mo=lane&15,
// q=lane>>4) holds [mo][k=32S+8q+kk]; C/D: col=lane&15, row=(lane>>4)*4+reg.

#define DIN 128
#define DOUT 128
#define KTOT 1024

typedef unsigned int u32;
typedef unsigned short u16;
typedef __attribute__((ext_vector_type(8))) short bf16x8;
typedef __attribute__((ext_vector_type(4))) float f32x4;

union H8 { u16 s[8]; uint4 v; };

__device__ __forceinline__ u16 f2b(float f) {
    union { __hip_bfloat16 h; u16 u; } c;
    c.h = __float2bfloat16(f);   // RNE
    return c.u;
}

// ---- K1: W'[o,k] = w[o,k>>3] * coeffs[o,k] as bf16 into ws (once) ----
__global__ __launch_bounds__(256) void kan_wprep(
    const float* __restrict__ coeffs, const float* __restrict__ weights,
    u16* __restrict__ wsW)
{
    const int gid = blockIdx.x * 256 + threadIdx.x;   // [0,16384) = o*128+j
    const float wv = weights[gid];                    // coalesced
    const float4 c0 = *(const float4*)(coeffs + gid * 8);
    const float4 c1 = *(const float4*)(coeffs + gid * 8 + 4);
    H8 h;
    h.s[0] = f2b(c0.x * wv); h.s[1] = f2b(c0.y * wv);
    h.s[2] = f2b(c0.z * wv); h.s[3] = f2b(c0.w * wv);
    h.s[4] = f2b(c1.x * wv); h.s[5] = f2b(c1.y * wv);
    h.s[6] = f2b(c1.z * wv); h.s[7] = f2b(c1.w * wv);
    *(uint4*)(wsW + gid * 8) = h.v;                   // coalesced 16B/lane
}

// ---- K2: fused basis-stage + pure-LDS MFMA GEMM ----
__global__ __launch_bounds__(1024) void kan_fused(
    const float* __restrict__ x, const u16* __restrict__ wsW,
    const float* __restrict__ bias, float* __restrict__ out)
{
    __shared__ __align__(16) u16 sBas[16 * KTOT];   // 32 KB (aliased by sC)
    __shared__ __align__(16) u16 sWp [16 * KTOT];   // 32 KB
    float* sC = (float*)sBas;                       // 16 KB partials (alias)

    const int tid  = threadIdx.x;
    const int wave = tid >> 6;                      // 0..15
    const int lane = tid & 63;

    // XCD-patch swizzle: id&7 ~ XCD (dispatch round-robin heuristic).
    // Each XCD class covers a contiguous 16m x 4o patch.
    const int id  = blockIdx.x;                     // 0..511
    const int xcd = id & 7;
    const int loc = id >> 3;                        // 0..63
    const int mt = ((xcd >> 1) << 4) | (loc & 15);  // 0..63
    const int ot = ((xcd & 1) << 2) | (loc >> 4);   // 0..7
    const int n0 = mt * 16;
    const int o0 = ot * 16;

    // ---- Phase 1a: basis tile. 2048 tasks (row,j), coalesced x reads ----
    #pragma unroll
    for (int it = 0; it < 2; ++it) {
        const int task = tid + it * 1024;           // row*128 + j
        const int row = task >> 7;
        const int j = task & 127;
        float xv = x[n0 * DIN + task];              // consecutive floats
        xv = fminf(fmaxf(xv, -1.0f), 1.0f);
        const float t = (xv + 1.0f) * 3.5f;         // h = 2/7
        int idx = (int)t; idx = idx > 6 ? 6 : idx;  // t>=0: trunc==floor
        const float u = t - (float)idx;
        const float u2 = u * u, u3 = u2 * u;
        const float b0 = 0.5f * (-u3 + 2.0f * u2 - u);
        const float b1 = 0.5f * (3.0f * u3 - 5.0f * u2 + 2.0f);
        const float b2 = 0.5f * (-3.0f * u3 + 4.0f * u2 + u);
        const float b3 = 0.5f * (u3 - u2);
        float r[8];
        #pragma unroll
        for (int k = 0; k < 8; ++k) r[k] = 0.0f;
        const int i0 = idx > 0 ? idx - 1 : 0;       // accumulate = clip fix
        const int i3 = idx < 6 ? idx + 2 : 7;
        r[i0] += b0; r[idx] += b1; r[idx + 1] += b2; r[i3] += b3;
        H8 h;
        #pragma unroll
        for (int k = 0; k < 8; ++k) h.s[k] = f2b(r[k]);
        const int uu = j ^ (row & 7);               // swizzled 16B unit
        *(uint4*)(sBas + row * KTOT + uu * 8) = h.v;
    }

    // ---- Phase 1b: W' tile. pure copy from ws, zero VALU ----
    #pragma unroll
    for (int it = 0; it < 2; ++it) {
        const int task = tid + it * 1024;           // row(o-local)*128 + unit
        const int row = task >> 7;
        const int u0 = task & 127;
        const uint4 v = *(const uint4*)(wsW + (o0 + row) * KTOT + u0 * 8);
        const int uu = u0 ^ (row & 7);
        *(uint4*)(sWp + row * KTOT + uu * 8) = v;
    }
    __syncthreads();

    // ---- Phase 2: pure LDS MFMA, wave = K-sixteenth (2 steps) ----
    const int mo = lane & 15;
    const int q  = lane >> 4;
    const int sw = mo & 7;                          // read-side swizzle
    f32x4 acc = {0.0f, 0.0f, 0.0f, 0.0f};
    #pragma unroll
    for (int s = 0; s < 2; ++s) {
        const int S = wave * 2 + s;                 // global K-step
        const int uu = (S * 4 + q) ^ sw;            // 16B unit
        bf16x8 af = *(const bf16x8*)(sBas + mo * KTOT + uu * 8);
        bf16x8 bf = *(const bf16x8*)(sWp  + mo * KTOT + uu * 8);
        acc = __builtin_amdgcn_mfma_f32_16x16x32_bf16(af, bf, acc, 0, 0, 0);
    }
    __syncthreads();                                // basis reads done

    // ---- Phase 3: 16-way reduce (sC aliases sBas) + bias + store ----
    #pragma unroll
    for (int r = 0; r < 4; ++r)
        sC[wave * 256 + (q * 4 + r) * 16 + mo] = acc[r];
    __syncthreads();

    if (tid < 256) {
        const int row = tid >> 4, col = tid & 15;
        float v = sC[tid];
        #pragma unroll
        for (int w = 1; w < 16; ++w) v += sC[w * 256 + tid];
        out[(n0 + row) * DOUT + o0 + col] = v + bias[o0 + col];
    }
}

extern "C" void kernel_launch(void* const* d_in, const int* in_sizes, int n_in,
                              void* d_out, int out_size, void* d_ws, size_t ws_size,
                              hipStream_t stream) {
    const float* x       = (const float*)d_in[0];
    const float* coeffs  = (const float*)d_in[1];
    const float* weights = (const float*)d_in[2];
    const float* bias    = (const float*)d_in[3];
    float* out = (float*)d_out;
    u16* wsW = (u16*)d_ws;                          // 256 KB W' (bf16)
    kan_wprep<<<DOUT * DIN / 256, 256, 0, stream>>>(coeffs, weights, wsW);
    kan_fused<<<512, 1024, 0, stream>>>(x, wsW, bias, out);
}

// Round 15
// 62.784 us; speedup vs baseline: 1.0482x; 1.0191x over previous
//
#include <hip/hip_runtime.h>
#include <hip/hip_bf16.h>
#include <stdint.h>

// KAN layer: out[n,o] = sum_j w[o,j] * spline(x[n,j]; coeffs[o,j,:]) + bias[o]
// N=1024, D_IN=128, D_OUT=128, K=8, Catmull-Rom, uniform grid [-1,1].
// fp32 in/out (proven R1/R2/R4).
//
// FINAL (R12 structure, best = 62.22us): fused single kernel.
//  - grid 64m x 8o = 512 blocks, 1024 threads (16 waves), 64KB LDS
//    -> 2 blocks/CU, 32 waves/CU (hardware max occupancy)
//  - phase 1: stage basis tile (16n x 1024k bf16; dense Catmull-Rom basis,
//    accumulate handles boundary clip) + W' tile (16o x 1024k bf16 = w*c)
//    from perfectly coalesced global reads; 2 iters/thread
//  - XOR swizzle (16B-unit ^ (row&7)): conflict-free writes, 2-way-aliased
//    reads (free, m136); no padding -> tiles exactly 64KB
//  - phase 2: pure LDS MFMA (zero global, zero VALU in chain), 16-way
//    K-split, 2 steps/wave
//  - phase 3: 16-way partial reduce (sC aliases basis tile) + bias + store
//
// Lever history: R10 pure-LDS MFMA -1.8; R11 512thr -0.95; R12 1024thr
// -0.16; R13 atomic K-split +3.6; R14 W'-precompute+XCD-swizzle +1.76.
// Budget: dur = ~52.4us harness (40us 268MB ws-poison fill @85% HBM peak +
// ~12us restores/fills) + ~9.8us kernel (resists 5 orthogonal attacks;
// work model ~2us; residual = cold-L2/dispatch latency).
//
// MFMA 16x16x32 bf16 (R5..R14-verified): A/B-frag lane (mo=lane&15,
// q=lane>>4) holds [mo][k=32S+8q+kk]; C/D: col=lane&15, row=(lane>>4)*4+reg.

#define DIN 128
#define DOUT 128
#define KTOT 1024

typedef unsigned int u32;
typedef unsigned short u16;
typedef __attribute__((ext_vector_type(8))) short bf16x8;
typedef __attribute__((ext_vector_type(4))) float f32x4;

union H8 { u16 s[8]; uint4 v; };

__device__ __forceinline__ u16 f2b(float f) {
    union { __hip_bfloat16 h; u16 u; } c;
    c.h = __float2bfloat16(f);   // RNE
    return c.u;
}

__global__ __launch_bounds__(1024) void kan_fused(
    const float* __restrict__ x, const float* __restrict__ coeffs,
    const float* __restrict__ weights, const float* __restrict__ bias,
    float* __restrict__ out)
{
    __shared__ __align__(16) u16 sBas[16 * KTOT];   // 32 KB (aliased by sC)
    __shared__ __align__(16) u16 sWp [16 * KTOT];   // 32 KB
    float* sC = (float*)sBas;                       // 16 KB partials (alias)

    const int tid  = threadIdx.x;
    const int wave = tid >> 6;                      // 0..15
    const int lane = tid & 63;
    const int n0 = blockIdx.x * 16;                 // 64 m-tiles
    const int o0 = blockIdx.y * 16;                 // 8 o-tiles

    // ---- Phase 1a: basis tile. 2048 tasks (row,j), coalesced x reads ----
    #pragma unroll
    for (int it = 0; it < 2; ++it) {
        const int task = tid + it * 1024;           // row*128 + j
        const int row = task >> 7;
        const int j = task & 127;
        float xv = x[n0 * DIN + task];              // consecutive floats
        xv = fminf(fmaxf(xv, -1.0f), 1.0f);
        const float t = (xv + 1.0f) * 3.5f;         // h = 2/7
        int idx = (int)t; idx = idx > 6 ? 6 : idx;  // t>=0: trunc==floor
        const float u = t - (float)idx;
        const float u2 = u * u, u3 = u2 * u;
        const float b0 = 0.5f * (-u3 + 2.0f * u2 - u);
        const float b1 = 0.5f * (3.0f * u3 - 5.0f * u2 + 2.0f);
        const float b2 = 0.5f * (-3.0f * u3 + 4.0f * u2 + u);
        const float b3 = 0.5f * (u3 - u2);
        float r[8];
        #pragma unroll
        for (int k = 0; k < 8; ++k) r[k] = 0.0f;
        const int i0 = idx > 0 ? idx - 1 : 0;       // accumulate = clip fix
        const int i3 = idx < 6 ? idx + 2 : 7;
        r[i0] += b0; r[idx] += b1; r[idx + 1] += b2; r[i3] += b3;
        H8 h;
        #pragma unroll
        for (int k = 0; k < 8; ++k) h.s[k] = f2b(r[k]);
        const int uu = j ^ (row & 7);               // swizzled 16B unit
        *(uint4*)(sBas + row * KTOT + uu * 8) = h.v;
    }

    // ---- Phase 1b: W' tile. 2048 tasks (o,j), coalesced 32B/lane ----
    #pragma unroll
    for (int it = 0; it < 2; ++it) {
        const int task = tid + it * 1024;           // o*128 + j
        const int o = task >> 7;
        const int j = task & 127;
        const float wv = weights[o0 * DIN + task];  // consecutive floats
        const float4 c0 = *(const float4*)(coeffs + o0 * KTOT + task * 8);
        const float4 c1 = *(const float4*)(coeffs + o0 * KTOT + task * 8 + 4);
        H8 h;
        h.s[0] = f2b(c0.x * wv); h.s[1] = f2b(c0.y * wv);
        h.s[2] = f2b(c0.z * wv); h.s[3] = f2b(c0.w * wv);
        h.s[4] = f2b(c1.x * wv); h.s[5] = f2b(c1.y * wv);
        h.s[6] = f2b(c1.z * wv); h.s[7] = f2b(c1.w * wv);
        const int uu = j ^ (o & 7);
        *(uint4*)(sWp + o * KTOT + uu * 8) = h.v;
    }
    __syncthreads();

    // ---- Phase 2: pure LDS MFMA, wave = K-sixteenth (2 steps) ----
    const int mo = lane & 15;
    const int q  = lane >> 4;
    const int sw = mo & 7;                          // read-side swizzle
    f32x4 acc = {0.0f, 0.0f, 0.0f, 0.0f};
    #pragma unroll
    for (int s = 0; s < 2; ++s) {
        const int S = wave * 2 + s;                 // global K-step
        const int uu = (S * 4 + q) ^ sw;            // 16B unit
        bf16x8 af = *(const bf16x8*)(sBas + mo * KTOT + uu * 8);
        bf16x8 bf = *(const bf16x8*)(sWp  + mo * KTOT + uu * 8);
        acc = __builtin_amdgcn_mfma_f32_16x16x32_bf16(af, bf, acc, 0, 0, 0);
    }
    __syncthreads();                                // basis reads done

    // ---- Phase 3: 16-way reduce (sC aliases sBas) + bias + store ----
    #pragma unroll
    for (int r = 0; r < 4; ++r)
        sC[wave * 256 + (q * 4 + r) * 16 + mo] = acc[r];
    __syncthreads();

    if (tid < 256) {
        const int row = tid >> 4, col = tid & 15;
        float v = sC[tid];
        #pragma unroll
        for (int w = 1; w < 16; ++w) v += sC[w * 256 + tid];
        out[(n0 + row) * DOUT + o0 + col] = v + bias[o0 + col];
    }
}

extern "C" void kernel_launch(void* const* d_in, const int* in_sizes, int n_in,
                              void* d_out, int out_size, void* d_ws, size_t ws_size,
                              hipStream_t stream) {
    const float* x       = (const float*)d_in[0];
    const float* coeffs  = (const float*)d_in[1];
    const float* weights = (const float*)d_in[2];
    const float* bias    = (const float*)d_in[3];
    float* out = (float*)d_out;
    const int N = in_sizes[0] / DIN;                // 1024
    dim3 grid(N / 16, DOUT / 16);                   // 64 x 8 = 512 blocks
    kan_fused<<<grid, 1024, 0, stream>>>(x, coeffs, weights, bias, out);
}